// Round 9
// baseline (464.721 us; speedup 1.0000x reference)
//
#include <hip/hip_runtime.h>

// Sizes (fixed by the problem)
#define NXc 256
#define NQc 256
#define NUc 128
#define Bc  8192
#define NHc 512
#define EPSc 0.001f

// ---------------------------------------------------------------------------
// Tiled f32 GEMM segment v2: accumulates a 64x64 C-tile over K.
// Block = 256 threads (16x16), 4x4 micro-tile, BK=32.
// ---------------------------------------------------------------------------
template<bool BT>
__device__ inline void gemm_seg(const float* __restrict__ A, int lda,
                                const float* __restrict__ Bm, int ldb,
                                int m0, int n0, int K,
                                float acc[4][4], float* As, float* Bs)
{
    const int tid = threadIdx.x;
    const int tx = tid & 15, ty = tid >> 4;
    const int ar  = tid >> 3;     // 0..31 (+32 on second pass)
    const int akc = tid & 7;      // float4 index along k
    for (int k0 = 0; k0 < K; k0 += 32) {
        __syncthreads();   // separates previous compute from new staging
        #pragma unroll
        for (int it = 0; it < 2; ++it) {
            const int r = ar + it * 32;
            const float4 a4 = *(const float4*)&A[(m0 + r) * lda + k0 + akc * 4];
            As[(akc * 4 + 0) * 68 + r] = a4.x;
            As[(akc * 4 + 1) * 68 + r] = a4.y;
            As[(akc * 4 + 2) * 68 + r] = a4.z;
            As[(akc * 4 + 3) * 68 + r] = a4.w;
        }
        if constexpr (BT) {
            #pragma unroll
            for (int it = 0; it < 2; ++it) {
                const int n = ar + it * 32;
                const float4 b4 = *(const float4*)&Bm[(n0 + n) * ldb + k0 + akc * 4];
                Bs[(akc * 4 + 0) * 68 + n] = b4.x;
                Bs[(akc * 4 + 1) * 68 + n] = b4.y;
                Bs[(akc * 4 + 2) * 68 + n] = b4.z;
                Bs[(akc * 4 + 3) * 68 + n] = b4.w;
            }
        } else {
            const int bn4 = tid & 15;   // n = bn4*4
            const int bk  = tid >> 4;   // 0..15 (+16 on second pass)
            #pragma unroll
            for (int it = 0; it < 2; ++it) {
                const int kk = bk + it * 16;
                *(float4*)&Bs[kk * 68 + bn4 * 4] =
                    *(const float4*)&Bm[(k0 + kk) * ldb + n0 + bn4 * 4];
            }
        }
        __syncthreads();
        #pragma unroll
        for (int kk = 0; kk < 32; ++kk) {
            const float4 a4 = *(const float4*)&As[kk * 68 + ty * 4];
            const float4 b4 = *(const float4*)&Bs[kk * 68 + tx * 4];
            const float av[4] = {a4.x, a4.y, a4.z, a4.w};
            const float bw[4] = {b4.x, b4.y, b4.z, b4.w};
            #pragma unroll
            for (int i = 0; i < 4; ++i)
                #pragma unroll
                for (int j = 0; j < 4; ++j)
                    acc[i][j] = __builtin_fmaf(av[i], bw[j], acc[i][j]);
        }
    }
}

// C = alpha * S @ S^T + EPS*I   (n x n, n multiple of 64)
__global__ __launch_bounds__(256) void k_gemm_sym(const float* __restrict__ S,
                                                  float* __restrict__ C,
                                                  int n, float alpha)
{
    __shared__ __align__(16) float As[32 * 68];
    __shared__ __align__(16) float Bs[32 * 68];
    float acc[4][4] = {};
    const int m0 = blockIdx.y * 64, n0 = blockIdx.x * 64;
    gemm_seg<true>(S, n, S, n, m0, n0, n, acc, As, Bs);
    const int tx = threadIdx.x & 15, ty = threadIdx.x >> 4;
    #pragma unroll
    for (int i = 0; i < 4; ++i)
        #pragma unroll
        for (int j = 0; j < 4; ++j) {
            int r = m0 + ty * 4 + i, c = n0 + tx * 4 + j;
            float v = alpha * acc[i][j];
            if (r == c) v += EPSc;
            C[r * n + c] = v;
        }
}

// From H (512x512), Chi, Y1: build YM = [Y | M] (256x512), D11 (256x256), linv (256)
__global__ void k_derive(const float* __restrict__ H, const float* __restrict__ Chi,
                         const float* __restrict__ Y1,
                         float* __restrict__ YM, float* __restrict__ D11,
                         float* __restrict__ linv)
{
    const int i = blockIdx.x;
    const int j = threadIdx.x;
    const float li = 2.0f / H[(256 + i) * 512 + 256 + i];
    YM[i * 512 + j] = -0.5f * (H[i * 512 + j] + Y1[i * 256 + j] - Y1[j * 256 + i]);
    YM[i * 512 + 256 + j] = -H[i * 512 + 256 + j] - Chi[i * 256 + j];
    D11[i * 256 + j] = (j < i) ? (-H[(256 + i) * 512 + 256 + j] * li) : 0.0f;
    if (j == 0) linv[i] = li;
}

// base = (xi @ Chi) * linv[col] + u @ D12^T + bv    -> basew (8192 x 256)
__global__ __launch_bounds__(256) void k_base(const float* __restrict__ xi,
                                              const float* __restrict__ u,
                                              const float* __restrict__ Chi,
                                              const float* __restrict__ D12,
                                              const float* __restrict__ bv,
                                              const float* __restrict__ linv,
                                              float* __restrict__ basew)
{
    __shared__ __align__(16) float As[32 * 68];
    __shared__ __align__(16) float Bs[32 * 68];
    float acc[4][4] = {};
    const int m0 = blockIdx.y * 64, n0 = blockIdx.x * 64;
    gemm_seg<false>(xi, 256, Chi, 256, m0, n0, 256, acc, As, Bs);
    const int tx = threadIdx.x & 15, ty = threadIdx.x >> 4;
    #pragma unroll
    for (int j = 0; j < 4; ++j) {
        float lv = linv[n0 + tx * 4 + j];
        #pragma unroll
        for (int i = 0; i < 4; ++i) acc[i][j] *= lv;
    }
    gemm_seg<true>(u, 128, D12, 128, m0, n0, 128, acc, As, Bs);
    #pragma unroll
    for (int i = 0; i < 4; ++i)
        #pragma unroll
        for (int j = 0; j < 4; ++j) {
            int r = m0 + ty * 4 + i, c = n0 + tx * 4 + j;
            basew[r * 256 + c] = acc[i][j] + bv[c];
        }
}

// ---------------------------------------------------------------------------
// GJ body v2.2: rank-4 blocked in-place Gauss-Jordan inverse (256x256, SPD,
// no pivoting). 64 rounds of 4 pivots; 2 barriers/round.
// v2.2: Rp panel register-cached once per round (rp[4][8], 32 ds_reads) so
// the 256-FMA bulk update runs entirely from registers (v2.1 re-read LDS
// inside the loop: 256 ds_reads/thread/round -> LDS-issue-bound, 340us).
// All register indexing compile-time static. lds: R[4][260] + Rp[4][260].
// ---------------------------------------------------------------------------
__device__ void gj_body(float* __restrict__ M, float* __restrict__ lds)
{
    float* R  = lds;            // 4*260
    float* Rp = lds + 4 * 260;  // 4*260
    const int tid = threadIdx.x;
    const int tx = tid & 31;
    const int ty = tid >> 5;
    float m[8][8];
    #pragma unroll
    for (int ii = 0; ii < 8; ++ii)
        #pragma unroll
        for (int jj = 0; jj < 8; ++jj)
            m[ii][jj] = M[(ty * 8 + ii) * 256 + tx + 32 * jj];

    if (ty == 0) {
        #pragma unroll
        for (int p = 0; p < 4; ++p)
            #pragma unroll
            for (int jj = 0; jj < 8; ++jj)
                R[p * 260 + tx + 32 * jj] = m[p][jj];
    }
    __syncthreads();

    #pragma unroll 1
    for (int g = 0; g < 64; ++g) {
        const int k0 = g * 4;
        const int jb0 = k0 >> 5;        // jj slot holding the pivot cols
        const int lt0 = k0 & 31;        // lanes lt0..lt0+3 own them
        // ---- Dinv: redundant per-thread 4x4 in-place GJ inverse
        float d[4][4];
        #pragma unroll
        for (int p = 0; p < 4; ++p)
            #pragma unroll
            for (int q = 0; q < 4; ++q)
                d[p][q] = R[p * 260 + k0 + q];
        #pragma unroll
        for (int k = 0; k < 4; ++k) {
            const float pinv = 1.0f / d[k][k];
            #pragma unroll
            for (int i = 0; i < 4; ++i) if (i != k) {
                const float f = d[i][k] * pinv;
                #pragma unroll
                for (int j = 0; j < 4; ++j) if (j != k)
                    d[i][j] = __builtin_fmaf(-f, d[k][j], d[i][j]);
                d[i][k] = -f;
            }
            #pragma unroll
            for (int j = 0; j < 4; ++j) if (j != k) d[k][j] *= pinv;
            d[k][k] = pinv;
        }
        // ---- R' = Dinv * R : one element per thread (static reg indices)
        {
            const int p = tid >> 8;      // 0..3
            const int col = tid & 255;
            float v = 0.f;
            #pragma unroll
            for (int pp = 0; pp < 4; ++pp) if (pp == p) {
                #pragma unroll
                for (int q = 0; q < 4; ++q)
                    v = __builtin_fmaf(d[pp][q], R[q * 260 + col], v);
            }
            Rp[p * 260 + col] = v;
        }
        __syncthreads();                 // R' ready
        // ---- cache Rp panel in registers (32 ds_reads, conflict-free)
        float rp[4][8];
        #pragma unroll
        for (int p = 0; p < 4; ++p)
            #pragma unroll
            for (int jj = 0; jj < 8; ++jj)
                rp[p][jj] = Rp[p * 260 + tx + 32 * jj];
        // ---- bulk rank-4 update: M -= C · Rp   (registers only)
        const bool panelOwner = (ty == (k0 >> 3));
        const int pii = k0 & 7;          // 0 or 4
        #pragma unroll
        for (int ii = 0; ii < 8; ++ii) {
            // gather this row's pivot-col values C[row][k0..k0+3]
            float mv = 0.f;
            #pragma unroll
            for (int jb = 0; jb < 8; ++jb) if (jb == jb0) mv = m[ii][jb];
            float ci[4];
            #pragma unroll
            for (int p = 0; p < 4; ++p)
                ci[p] = __shfl(mv, (tid & 32) | (lt0 + p));
            // fi = (C · Dinv)[row][p]  -- used ONLY for the pivot-col patch
            float fi[4];
            #pragma unroll
            for (int p = 0; p < 4; ++p) {
                float s = 0.f;
                #pragma unroll
                for (int q = 0; q < 4; ++q)
                    s = __builtin_fmaf(ci[q], d[q][p], s);
                fi[p] = s;
            }
            #pragma unroll
            for (int jj = 0; jj < 8; ++jj) {
                float upd = m[ii][jj];
                #pragma unroll
                for (int p = 0; p < 4; ++p)
                    upd = __builtin_fmaf(-ci[p], rp[p][jj], upd);
                if (jj == jb0) {         // pivot-col entries: -C*Dinv
                    #pragma unroll
                    for (int p = 0; p < 4; ++p)
                        if (tx == lt0 + p) upd = -fi[p];
                }
                m[ii][jj] = upd;
            }
            // panel rows: overwrite with R' (and Dinv at pivot cols)
            if (panelOwner) {
                #pragma unroll
                for (int pp = 0; pp < 4; ++pp) if (ii == pii + pp) {
                    #pragma unroll
                    for (int jj = 0; jj < 8; ++jj) {
                        float nv = rp[pp][jj];
                        if (jj == jb0) {
                            #pragma unroll
                            for (int p = 0; p < 4; ++p)
                                if (tx == lt0 + p) nv = d[pp][p];
                        }
                        m[ii][jj] = nv;
                    }
                }
            }
        }
        // ---- stage next round's pivot rows (post-update values)
        const int k1 = k0 + 4;
        if (k1 < 256 && ty == (k1 >> 3)) {
            const int pii1 = k1 & 7;
            #pragma unroll
            for (int ii = 0; ii < 8; ++ii)
                #pragma unroll
                for (int pp = 0; pp < 4; ++pp) if (ii == pii1 + pp)
                    #pragma unroll
                    for (int jj = 0; jj < 8; ++jj)
                        R[pp * 260 + tx + 32 * jj] = m[ii][jj];
        }
        __syncthreads();
    }

    #pragma unroll
    for (int ii = 0; ii < 8; ++ii)
        #pragma unroll
        for (int jj = 0; jj < 8; ++jj)
            M[(ty * 8 + ii) * 256 + tx + 32 * jj] = m[ii][jj];
}

// ---------------------------------------------------------------------------
// Scan body v4 (1024 threads, 32 lanes per batch-row):
//   w[:,i] = tanh(base[:,i] + sum_{j<i} w[:,j]*D11[i][j])
// ---------------------------------------------------------------------------
#define WPAD 264
__device__ void scan_body(const float* __restrict__ d11,
                          float* __restrict__ basew, int blk,
                          float* __restrict__ wls, float* __restrict__ dblk)
{
    const int tid = threadIdx.x;
    const int row0 = blk * 32;
    for (int idx = tid; idx < 32 * 64; idx += 1024) {
        int r = idx >> 6, c4 = idx & 63;
        *(float4*)&wls[r * WPAD + c4 * 4] =
            *(const float4*)&basew[(row0 + r) * 256 + c4 * 4];
    }
    __syncthreads();

    const int r = tid >> 5;
    const int t = tid & 31;
    float* rowp = &wls[r * WPAD];
    const int sr = tid >> 3, sc4 = tid & 7;   // dblk staging coords (tid<256)

    #pragma unroll 1
    for (int c = 0; c < 8; ++c) {
        const int i0 = 32 * c;
        if (tid < 256) {   // stage D11 diag 32x32 block
            const float4 dv4 = *(const float4*)&d11[(i0 + sr) * 256 + i0 + sc4 * 4];
            dblk[sr * 33 + sc4 * 4 + 0] = dv4.x;
            dblk[sr * 33 + sc4 * 4 + 1] = dv4.y;
            dblk[sr * 33 + sc4 * 4 + 2] = dv4.z;
            dblk[sr * 33 + sc4 * 4 + 3] = dv4.w;
        }
        // dense history: acc = base + sum_{j<i0} w[j] * D11[i0+t][j]
        float acc = rowp[i0 + t];
        const float* d0 = d11 + (i0 + t) * 256;
        for (int j = 0; j < i0; j += 4) {
            const float4 w4 = *(const float4*)&rowp[j];
            const float4 dv = *(const float4*)&d0[j];
            acc = __builtin_fmaf(w4.x, dv.x, acc);
            acc = __builtin_fmaf(w4.y, dv.y, acc);
            acc = __builtin_fmaf(w4.z, dv.z, acc);
            acc = __builtin_fmaf(w4.w, dv.w, acc);
        }
        __syncthreads();              // dblk staged
        // serial: 32 steps; lane t's acc is final when jj reaches t
        #pragma unroll
        for (int jj = 0; jj < 32; ++jj) {
            const float v = 1.0f - 2.0f / (__expf(2.0f * acc) + 1.0f);
            const float wj = __shfl(v, jj, 32);   // broadcast from owner
            if (t == jj) rowp[i0 + jj] = v;       // off-chain store
            if (t > jj) acc = __builtin_fmaf(wj, dblk[t * 33 + jj], acc);
        }
        __syncthreads();              // dblk free for next c
    }

    for (int idx = tid; idx < 32 * 64; idx += 1024) {
        int rr = idx >> 6, c4 = idx & 63;
        *(float4*)&basew[(row0 + rr) * 256 + c4 * 4] =
            *(const float4*)&wls[rr * WPAD + c4 * 4];
    }
}

// ---------------------------------------------------------------------------
// Fat kernel: block 0 runs the 1-CU Gauss-Jordan inverse while blocks 1..256
// run the scan. Barriers are per-block; bodies touch disjoint buffers.
// ---------------------------------------------------------------------------
__global__ __launch_bounds__(1024) void k_fat(float* __restrict__ Pm,
                                              const float* __restrict__ d11,
                                              float* __restrict__ basew)
{
    __shared__ __align__(16) float shmem[32 * WPAD + 32 * 33];
    if (blockIdx.x == 0) {
        gj_body(Pm, shmem);                       // uses 2*4*260 floats
    } else {
        scan_body(d11, basew, blockIdx.x - 1, shmem, shmem + 32 * WPAD);
    }
}

// AB = Pinv @ [Y | M]   (256 x 512): rows give A[x][k] and B1[x][q] directly
__global__ __launch_bounds__(256) void k_ab(const float* __restrict__ Pinv,
                                            const float* __restrict__ YM,
                                            float* __restrict__ AB)
{
    __shared__ __align__(16) float As[32 * 68];
    __shared__ __align__(16) float Bs[32 * 68];
    float acc[4][4] = {};
    const int m0 = blockIdx.y * 64, n0 = blockIdx.x * 64;
    gemm_seg<false>(Pinv, 256, YM, 512, m0, n0, 256, acc, As, Bs);
    const int tx = threadIdx.x & 15, ty = threadIdx.x >> 4;
    #pragma unroll
    for (int i = 0; i < 4; ++i)
        #pragma unroll
        for (int j = 0; j < 4; ++j)
            AB[(m0 + ty * 4 + i) * 512 + n0 + tx * 4 + j] = acc[i][j];
}

// xi_dot = xi @ A^T + w @ B1^T + u @ B2^T + bx
__global__ __launch_bounds__(256) void k_final(const float* __restrict__ xi,
                                               const float* __restrict__ w,
                                               const float* __restrict__ u,
                                               const float* __restrict__ AB,
                                               const float* __restrict__ B2,
                                               const float* __restrict__ bx,
                                               float* __restrict__ out)
{
    __shared__ __align__(16) float As[32 * 68];
    __shared__ __align__(16) float Bs[32 * 68];
    float acc[4][4] = {};
    const int m0 = blockIdx.y * 64, n0 = blockIdx.x * 64;
    gemm_seg<true>(xi, 256, AB, 512, m0, n0, 256, acc, As, Bs);        // A-part
    gemm_seg<true>(w, 256, AB + 256, 512, m0, n0, 256, acc, As, Bs);   // B1-part
    gemm_seg<true>(u, 128, B2, 128, m0, n0, 128, acc, As, Bs);         // B2-part
    const int tx = threadIdx.x & 15, ty = threadIdx.x >> 4;
    #pragma unroll
    for (int i = 0; i < 4; ++i)
        #pragma unroll
        for (int j = 0; j < 4; ++j) {
            int r = m0 + ty * 4 + i, c = n0 + tx * 4 + j;
            out[r * 256 + c] = acc[i][j] + bx[c];
        }
}

extern "C" void kernel_launch(void* const* d_in, const int* in_sizes, int n_in,
                              void* d_out, int out_size, void* d_ws, size_t ws_size,
                              hipStream_t stream)
{
    (void)in_sizes; (void)n_in; (void)out_size; (void)ws_size;
    // setup_inputs order: t, xi, u, Pstar, Chi, Y1, B2, D12, X, bx, bv
    const float* xi    = (const float*)d_in[1];
    const float* u     = (const float*)d_in[2];
    const float* Pstar = (const float*)d_in[3];
    const float* Chi   = (const float*)d_in[4];
    const float* Y1    = (const float*)d_in[5];
    const float* B2    = (const float*)d_in[6];
    const float* D12   = (const float*)d_in[7];
    const float* X     = (const float*)d_in[8];
    const float* bx    = (const float*)d_in[9];
    const float* bv    = (const float*)d_in[10];
    float* out = (float*)d_out;

    float* ws    = (float*)d_ws;
    float* H     = ws;              // 512*512   = 262144
    float* YM    = H + 262144;      // 256*512   = 131072
    float* D11   = YM + 131072;     // 256*256   =  65536
    float* linv  = D11 + 65536;     // 256
    float* Pm    = linv + 256;      // 256*256   =  65536  (becomes Pinv)
    float* AB    = Pm + 65536;      // 256*512   = 131072
    float* basew = AB + 131072;     // 8192*256  = 2097152 (base, then w in-place)

    k_gemm_sym<<<dim3(8, 8), 256, 0, stream>>>(X, H, 512, 1.0f);         // H
    k_gemm_sym<<<dim3(4, 4), 256, 0, stream>>>(Pstar, Pm, 256, 0.5f);    // P
    k_derive  <<<dim3(256), 256, 0, stream>>>(H, Chi, Y1, YM, D11, linv);
    k_base    <<<dim3(4, 128), 256, 0, stream>>>(xi, u, Chi, D12, bv, linv, basew);
    k_fat     <<<dim3(257), 1024, 0, stream>>>(Pm, D11, basew);          // GJ || scan
    k_ab      <<<dim3(8, 4), 256, 0, stream>>>(Pm, YM, AB);              // [A | B1]
    k_final   <<<dim3(4, 128), 256, 0, stream>>>(xi, basew, u, AB, B2, bx, out);
}

// Round 10
// 448.378 us; speedup vs baseline: 1.0364x; 1.0364x over previous
//
#include <hip/hip_runtime.h>

// Sizes (fixed by the problem)
#define NXc 256
#define NQc 256
#define NUc 128
#define Bc  8192
#define NHc 512
#define EPSc 0.001f

// ---------------------------------------------------------------------------
// Tiled f32 GEMM segment v2: accumulates a 64x64 C-tile over K.
// Block = 256 threads (16x16), 4x4 micro-tile, BK=32.
// ---------------------------------------------------------------------------
template<bool BT>
__device__ inline void gemm_seg(const float* __restrict__ A, int lda,
                                const float* __restrict__ Bm, int ldb,
                                int m0, int n0, int K,
                                float acc[4][4], float* As, float* Bs)
{
    const int tid = threadIdx.x;
    const int tx = tid & 15, ty = tid >> 4;
    const int ar  = tid >> 3;     // 0..31 (+32 on second pass)
    const int akc = tid & 7;      // float4 index along k
    for (int k0 = 0; k0 < K; k0 += 32) {
        __syncthreads();   // separates previous compute from new staging
        #pragma unroll
        for (int it = 0; it < 2; ++it) {
            const int r = ar + it * 32;
            const float4 a4 = *(const float4*)&A[(m0 + r) * lda + k0 + akc * 4];
            As[(akc * 4 + 0) * 68 + r] = a4.x;
            As[(akc * 4 + 1) * 68 + r] = a4.y;
            As[(akc * 4 + 2) * 68 + r] = a4.z;
            As[(akc * 4 + 3) * 68 + r] = a4.w;
        }
        if constexpr (BT) {
            #pragma unroll
            for (int it = 0; it < 2; ++it) {
                const int n = ar + it * 32;
                const float4 b4 = *(const float4*)&Bm[(n0 + n) * ldb + k0 + akc * 4];
                Bs[(akc * 4 + 0) * 68 + n] = b4.x;
                Bs[(akc * 4 + 1) * 68 + n] = b4.y;
                Bs[(akc * 4 + 2) * 68 + n] = b4.z;
                Bs[(akc * 4 + 3) * 68 + n] = b4.w;
            }
        } else {
            const int bn4 = tid & 15;   // n = bn4*4
            const int bk  = tid >> 4;   // 0..15 (+16 on second pass)
            #pragma unroll
            for (int it = 0; it < 2; ++it) {
                const int kk = bk + it * 16;
                *(float4*)&Bs[kk * 68 + bn4 * 4] =
                    *(const float4*)&Bm[(k0 + kk) * ldb + n0 + bn4 * 4];
            }
        }
        __syncthreads();
        #pragma unroll
        for (int kk = 0; kk < 32; ++kk) {
            const float4 a4 = *(const float4*)&As[kk * 68 + ty * 4];
            const float4 b4 = *(const float4*)&Bs[kk * 68 + tx * 4];
            const float av[4] = {a4.x, a4.y, a4.z, a4.w};
            const float bw[4] = {b4.x, b4.y, b4.z, b4.w};
            #pragma unroll
            for (int i = 0; i < 4; ++i)
                #pragma unroll
                for (int j = 0; j < 4; ++j)
                    acc[i][j] = __builtin_fmaf(av[i], bw[j], acc[i][j]);
        }
    }
}

// C = alpha * S @ S^T + EPS*I   (n x n, n multiple of 64)
__global__ __launch_bounds__(256) void k_gemm_sym(const float* __restrict__ S,
                                                  float* __restrict__ C,
                                                  int n, float alpha)
{
    __shared__ __align__(16) float As[32 * 68];
    __shared__ __align__(16) float Bs[32 * 68];
    float acc[4][4] = {};
    const int m0 = blockIdx.y * 64, n0 = blockIdx.x * 64;
    gemm_seg<true>(S, n, S, n, m0, n0, n, acc, As, Bs);
    const int tx = threadIdx.x & 15, ty = threadIdx.x >> 4;
    #pragma unroll
    for (int i = 0; i < 4; ++i)
        #pragma unroll
        for (int j = 0; j < 4; ++j) {
            int r = m0 + ty * 4 + i, c = n0 + tx * 4 + j;
            float v = alpha * acc[i][j];
            if (r == c) v += EPSc;
            C[r * n + c] = v;
        }
}

// From H (512x512), Chi, Y1: build YM = [Y | M] (256x512), D11 (256x256), linv (256)
__global__ void k_derive(const float* __restrict__ H, const float* __restrict__ Chi,
                         const float* __restrict__ Y1,
                         float* __restrict__ YM, float* __restrict__ D11,
                         float* __restrict__ linv)
{
    const int i = blockIdx.x;
    const int j = threadIdx.x;
    const float li = 2.0f / H[(256 + i) * 512 + 256 + i];
    YM[i * 512 + j] = -0.5f * (H[i * 512 + j] + Y1[i * 256 + j] - Y1[j * 256 + i]);
    YM[i * 512 + 256 + j] = -H[i * 512 + 256 + j] - Chi[i * 256 + j];
    D11[i * 256 + j] = (j < i) ? (-H[(256 + i) * 512 + 256 + j] * li) : 0.0f;
    if (j == 0) linv[i] = li;
}

// base = (xi @ Chi) * linv[col] + u @ D12^T + bv    -> basew (8192 x 256)
__global__ __launch_bounds__(256) void k_base(const float* __restrict__ xi,
                                              const float* __restrict__ u,
                                              const float* __restrict__ Chi,
                                              const float* __restrict__ D12,
                                              const float* __restrict__ bv,
                                              const float* __restrict__ linv,
                                              float* __restrict__ basew)
{
    __shared__ __align__(16) float As[32 * 68];
    __shared__ __align__(16) float Bs[32 * 68];
    float acc[4][4] = {};
    const int m0 = blockIdx.y * 64, n0 = blockIdx.x * 64;
    gemm_seg<false>(xi, 256, Chi, 256, m0, n0, 256, acc, As, Bs);
    const int tx = threadIdx.x & 15, ty = threadIdx.x >> 4;
    #pragma unroll
    for (int j = 0; j < 4; ++j) {
        float lv = linv[n0 + tx * 4 + j];
        #pragma unroll
        for (int i = 0; i < 4; ++i) acc[i][j] *= lv;
    }
    gemm_seg<true>(u, 128, D12, 128, m0, n0, 128, acc, As, Bs);
    #pragma unroll
    for (int i = 0; i < 4; ++i)
        #pragma unroll
        for (int j = 0; j < 4; ++j) {
            int r = m0 + ty * 4 + i, c = n0 + tx * 4 + j;
            basew[r * 256 + c] = acc[i][j] + bv[c];
        }
}

// ---------------------------------------------------------------------------
// GJ body v2.3: rank-4 blocked in-place Gauss-Jordan inverse (256x256, SPD,
// no pivoting). 64 rounds of 4 pivots; 2 barriers/round.
// v2.3: fi (=C*Dinv, pivot-col patch) computed only in the 4 pivot lanes.
// Requires the enclosing kernel to use __launch_bounds__(1024, 1) so the
// ~160 floats of per-thread state (m[8][8], rp, d) fit in registers
// (default heuristic allocated 64 VGPR -> spill -> 340us flat).
// ---------------------------------------------------------------------------
__device__ void gj_body(float* __restrict__ M, float* __restrict__ lds)
{
    float* R  = lds;            // 4*260
    float* Rp = lds + 4 * 260;  // 4*260
    const int tid = threadIdx.x;
    const int tx = tid & 31;
    const int ty = tid >> 5;
    float m[8][8];
    #pragma unroll
    for (int ii = 0; ii < 8; ++ii)
        #pragma unroll
        for (int jj = 0; jj < 8; ++jj)
            m[ii][jj] = M[(ty * 8 + ii) * 256 + tx + 32 * jj];

    if (ty == 0) {
        #pragma unroll
        for (int p = 0; p < 4; ++p)
            #pragma unroll
            for (int jj = 0; jj < 8; ++jj)
                R[p * 260 + tx + 32 * jj] = m[p][jj];
    }
    __syncthreads();

    #pragma unroll 1
    for (int g = 0; g < 64; ++g) {
        const int k0 = g * 4;
        const int jb0 = k0 >> 5;        // jj slot holding the pivot cols
        const int lt0 = k0 & 31;        // lanes lt0..lt0+3 own them
        // ---- Dinv: redundant per-thread 4x4 in-place GJ inverse
        float d[4][4];
        #pragma unroll
        for (int p = 0; p < 4; ++p)
            #pragma unroll
            for (int q = 0; q < 4; ++q)
                d[p][q] = R[p * 260 + k0 + q];
        #pragma unroll
        for (int k = 0; k < 4; ++k) {
            const float pinv = 1.0f / d[k][k];
            #pragma unroll
            for (int i = 0; i < 4; ++i) if (i != k) {
                const float f = d[i][k] * pinv;
                #pragma unroll
                for (int j = 0; j < 4; ++j) if (j != k)
                    d[i][j] = __builtin_fmaf(-f, d[k][j], d[i][j]);
                d[i][k] = -f;
            }
            #pragma unroll
            for (int j = 0; j < 4; ++j) if (j != k) d[k][j] *= pinv;
            d[k][k] = pinv;
        }
        // ---- R' = Dinv * R : one element per thread (static reg indices)
        {
            const int p = tid >> 8;      // 0..3
            const int col = tid & 255;
            float v = 0.f;
            #pragma unroll
            for (int pp = 0; pp < 4; ++pp) if (pp == p) {
                #pragma unroll
                for (int q = 0; q < 4; ++q)
                    v = __builtin_fmaf(d[pp][q], R[q * 260 + col], v);
            }
            Rp[p * 260 + col] = v;
        }
        __syncthreads();                 // R' ready
        // ---- cache Rp panel in registers (32 ds_reads, conflict-free)
        float rp[4][8];
        #pragma unroll
        for (int p = 0; p < 4; ++p)
            #pragma unroll
            for (int jj = 0; jj < 8; ++jj)
                rp[p][jj] = Rp[p * 260 + tx + 32 * jj];
        // ---- bulk rank-4 update: M -= C · Rp   (registers only)
        const bool panelOwner = (ty == (k0 >> 3));
        const int pii = k0 & 7;          // 0 or 4
        const int plane = tx - lt0;      // 0..3 for pivot-col lanes
        #pragma unroll
        for (int ii = 0; ii < 8; ++ii) {
            // gather this row's pivot-col values C[row][k0..k0+3]
            float mv = 0.f;
            #pragma unroll
            for (int jb = 0; jb < 8; ++jb) if (jb == jb0) mv = m[ii][jb];
            float ci[4];
            #pragma unroll
            for (int p = 0; p < 4; ++p)
                ci[p] = __shfl(mv, (tid & 32) | (lt0 + p));
            // fi = (C·Dinv)[row][plane] -- only pivot lanes need it
            float fiv = 0.f;
            if (plane >= 0 && plane < 4) {
                #pragma unroll
                for (int p = 0; p < 4; ++p) if (p == plane) {
                    #pragma unroll
                    for (int q = 0; q < 4; ++q)
                        fiv = __builtin_fmaf(ci[q], d[q][p], fiv);
                }
            }
            #pragma unroll
            for (int jj = 0; jj < 8; ++jj) {
                float upd = m[ii][jj];
                #pragma unroll
                for (int p = 0; p < 4; ++p)
                    upd = __builtin_fmaf(-ci[p], rp[p][jj], upd);
                if (jj == jb0 && plane >= 0 && plane < 4)
                    upd = -fiv;          // pivot-col entries: -C*Dinv
                m[ii][jj] = upd;
            }
            // panel rows: overwrite with R' (and Dinv at pivot cols)
            if (panelOwner) {
                #pragma unroll
                for (int pp = 0; pp < 4; ++pp) if (ii == pii + pp) {
                    #pragma unroll
                    for (int jj = 0; jj < 8; ++jj) {
                        float nv = rp[pp][jj];
                        if (jj == jb0) {
                            #pragma unroll
                            for (int p = 0; p < 4; ++p)
                                if (tx == lt0 + p) nv = d[pp][p];
                        }
                        m[ii][jj] = nv;
                    }
                }
            }
        }
        // ---- stage next round's pivot rows (post-update values)
        const int k1 = k0 + 4;
        if (k1 < 256 && ty == (k1 >> 3)) {
            const int pii1 = k1 & 7;
            #pragma unroll
            for (int ii = 0; ii < 8; ++ii)
                #pragma unroll
                for (int pp = 0; pp < 4; ++pp) if (ii == pii1 + pp)
                    #pragma unroll
                    for (int jj = 0; jj < 8; ++jj)
                        R[pp * 260 + tx + 32 * jj] = m[ii][jj];
        }
        __syncthreads();
    }

    #pragma unroll
    for (int ii = 0; ii < 8; ++ii)
        #pragma unroll
        for (int jj = 0; jj < 8; ++jj)
            M[(ty * 8 + ii) * 256 + tx + 32 * jj] = m[ii][jj];
}

// ---------------------------------------------------------------------------
// Scan body v4 (1024 threads, 32 lanes per batch-row):
//   w[:,i] = tanh(base[:,i] + sum_{j<i} w[:,j]*D11[i][j])
// ---------------------------------------------------------------------------
#define WPAD 264
__device__ void scan_body(const float* __restrict__ d11,
                          float* __restrict__ basew, int blk,
                          float* __restrict__ wls, float* __restrict__ dblk)
{
    const int tid = threadIdx.x;
    const int row0 = blk * 32;
    for (int idx = tid; idx < 32 * 64; idx += 1024) {
        int r = idx >> 6, c4 = idx & 63;
        *(float4*)&wls[r * WPAD + c4 * 4] =
            *(const float4*)&basew[(row0 + r) * 256 + c4 * 4];
    }
    __syncthreads();

    const int r = tid >> 5;
    const int t = tid & 31;
    float* rowp = &wls[r * WPAD];
    const int sr = tid >> 3, sc4 = tid & 7;   // dblk staging coords (tid<256)

    #pragma unroll 1
    for (int c = 0; c < 8; ++c) {
        const int i0 = 32 * c;
        if (tid < 256) {   // stage D11 diag 32x32 block
            const float4 dv4 = *(const float4*)&d11[(i0 + sr) * 256 + i0 + sc4 * 4];
            dblk[sr * 33 + sc4 * 4 + 0] = dv4.x;
            dblk[sr * 33 + sc4 * 4 + 1] = dv4.y;
            dblk[sr * 33 + sc4 * 4 + 2] = dv4.z;
            dblk[sr * 33 + sc4 * 4 + 3] = dv4.w;
        }
        // dense history: acc = base + sum_{j<i0} w[j] * D11[i0+t][j]
        float acc = rowp[i0 + t];
        const float* d0 = d11 + (i0 + t) * 256;
        for (int j = 0; j < i0; j += 4) {
            const float4 w4 = *(const float4*)&rowp[j];
            const float4 dv = *(const float4*)&d0[j];
            acc = __builtin_fmaf(w4.x, dv.x, acc);
            acc = __builtin_fmaf(w4.y, dv.y, acc);
            acc = __builtin_fmaf(w4.z, dv.z, acc);
            acc = __builtin_fmaf(w4.w, dv.w, acc);
        }
        __syncthreads();              // dblk staged
        // serial: 32 steps; lane t's acc is final when jj reaches t
        #pragma unroll
        for (int jj = 0; jj < 32; ++jj) {
            const float v = 1.0f - 2.0f / (__expf(2.0f * acc) + 1.0f);
            const float wj = __shfl(v, jj, 32);   // broadcast from owner
            if (t == jj) rowp[i0 + jj] = v;       // off-chain store
            if (t > jj) acc = __builtin_fmaf(wj, dblk[t * 33 + jj], acc);
        }
        __syncthreads();              // dblk free for next c
    }

    for (int idx = tid; idx < 32 * 64; idx += 1024) {
        int rr = idx >> 6, c4 = idx & 63;
        *(float4*)&basew[(row0 + rr) * 256 + c4 * 4] =
            *(const float4*)&wls[rr * WPAD + c4 * 4];
    }
}

// ---------------------------------------------------------------------------
// Fat kernel: block 0 runs the 1-CU Gauss-Jordan inverse while blocks 1..256
// run the scan. __launch_bounds__(1024, 1): allow max VGPR so gj_body's
// per-thread state stays in registers (default heuristic spilled it).
// ---------------------------------------------------------------------------
__global__ __launch_bounds__(1024, 1) void k_fat(float* __restrict__ Pm,
                                                 const float* __restrict__ d11,
                                                 float* __restrict__ basew)
{
    __shared__ __align__(16) float shmem[32 * WPAD + 32 * 33];
    if (blockIdx.x == 0) {
        gj_body(Pm, shmem);                       // uses 2*4*260 floats
    } else {
        scan_body(d11, basew, blockIdx.x - 1, shmem, shmem + 32 * WPAD);
    }
}

// AB = Pinv @ [Y | M]   (256 x 512): rows give A[x][k] and B1[x][q] directly
__global__ __launch_bounds__(256) void k_ab(const float* __restrict__ Pinv,
                                            const float* __restrict__ YM,
                                            float* __restrict__ AB)
{
    __shared__ __align__(16) float As[32 * 68];
    __shared__ __align__(16) float Bs[32 * 68];
    float acc[4][4] = {};
    const int m0 = blockIdx.y * 64, n0 = blockIdx.x * 64;
    gemm_seg<false>(Pinv, 256, YM, 512, m0, n0, 256, acc, As, Bs);
    const int tx = threadIdx.x & 15, ty = threadIdx.x >> 4;
    #pragma unroll
    for (int i = 0; i < 4; ++i)
        #pragma unroll
        for (int j = 0; j < 4; ++j)
            AB[(m0 + ty * 4 + i) * 512 + n0 + tx * 4 + j] = acc[i][j];
}

// xi_dot = xi @ A^T + w @ B1^T + u @ B2^T + bx
__global__ __launch_bounds__(256) void k_final(const float* __restrict__ xi,
                                               const float* __restrict__ w,
                                               const float* __restrict__ u,
                                               const float* __restrict__ AB,
                                               const float* __restrict__ B2,
                                               const float* __restrict__ bx,
                                               float* __restrict__ out)
{
    __shared__ __align__(16) float As[32 * 68];
    __shared__ __align__(16) float Bs[32 * 68];
    float acc[4][4] = {};
    const int m0 = blockIdx.y * 64, n0 = blockIdx.x * 64;
    gemm_seg<true>(xi, 256, AB, 512, m0, n0, 256, acc, As, Bs);        // A-part
    gemm_seg<true>(w, 256, AB + 256, 512, m0, n0, 256, acc, As, Bs);   // B1-part
    gemm_seg<true>(u, 128, B2, 128, m0, n0, 128, acc, As, Bs);         // B2-part
    const int tx = threadIdx.x & 15, ty = threadIdx.x >> 4;
    #pragma unroll
    for (int i = 0; i < 4; ++i)
        #pragma unroll
        for (int j = 0; j < 4; ++j) {
            int r = m0 + ty * 4 + i, c = n0 + tx * 4 + j;
            out[r * 256 + c] = acc[i][j] + bx[c];
        }
}

extern "C" void kernel_launch(void* const* d_in, const int* in_sizes, int n_in,
                              void* d_out, int out_size, void* d_ws, size_t ws_size,
                              hipStream_t stream)
{
    (void)in_sizes; (void)n_in; (void)out_size; (void)ws_size;
    // setup_inputs order: t, xi, u, Pstar, Chi, Y1, B2, D12, X, bx, bv
    const float* xi    = (const float*)d_in[1];
    const float* u     = (const float*)d_in[2];
    const float* Pstar = (const float*)d_in[3];
    const float* Chi   = (const float*)d_in[4];
    const float* Y1    = (const float*)d_in[5];
    const float* B2    = (const float*)d_in[6];
    const float* D12   = (const float*)d_in[7];
    const float* X     = (const float*)d_in[8];
    const float* bx    = (const float*)d_in[9];
    const float* bv    = (const float*)d_in[10];
    float* out = (float*)d_out;

    float* ws    = (float*)d_ws;
    float* H     = ws;              // 512*512   = 262144
    float* YM    = H + 262144;      // 256*512   = 131072
    float* D11   = YM + 131072;     // 256*256   =  65536
    float* linv  = D11 + 65536;     // 256
    float* Pm    = linv + 256;      // 256*256   =  65536  (becomes Pinv)
    float* AB    = Pm + 65536;      // 256*512   = 131072
    float* basew = AB + 131072;     // 8192*256  = 2097152 (base, then w in-place)

    k_gemm_sym<<<dim3(8, 8), 256, 0, stream>>>(X, H, 512, 1.0f);         // H
    k_gemm_sym<<<dim3(4, 4), 256, 0, stream>>>(Pstar, Pm, 256, 0.5f);    // P
    k_derive  <<<dim3(256), 256, 0, stream>>>(H, Chi, Y1, YM, D11, linv);
    k_base    <<<dim3(4, 128), 256, 0, stream>>>(xi, u, Chi, D12, bv, linv, basew);
    k_fat     <<<dim3(257), 1024, 0, stream>>>(Pm, D11, basew);          // GJ || scan
    k_ab      <<<dim3(8, 4), 256, 0, stream>>>(Pm, YM, AB);              // [A | B1]
    k_final   <<<dim3(4, 128), 256, 0, stream>>>(xi, basew, u, AB, B2, bx, out);
}